// Round 13
// baseline (262.652 us; speedup 1.0000x reference)
//
#include <hip/hip_runtime.h>
#include <cstdint>
#include <cstddef>

#define M_DIM 4096
#define K_DIM 4096
#define N_DIM 11008
#define BM 128
#define BN 256
#define BKB 64                        /* K bytes per step (one K=64 slice) */
#define NT (K_DIM / BKB)              /* 64 steps */
#define NTM (M_DIM / BM)              /* 32 */
#define NTN (N_DIM / BN)              /* 43 */
#define A_OFF 49152                   /* B ring-3 (3x16KB) first, then A ring-4 */
#define ABASE(k) (A_OFF + ((k) & 3) * 8192)

typedef int   int4v   __attribute__((ext_vector_type(4)));
typedef float float4v __attribute__((ext_vector_type(4)));

__device__ __forceinline__ void gload_lds16(const void* g, void* l) {
  __builtin_amdgcn_global_load_lds(
      (const __attribute__((address_space(1))) unsigned int*)g,
      (__attribute__((address_space(3))) unsigned int*)l, 16, 0, 0);
}

// ---------------- x quantization: fp32 -> int8 ----------------
__global__ void quant_x_kernel(const float* __restrict__ x,
                               const float* __restrict__ scale_p,
                               const int* __restrict__ off_p,
                               signed char* __restrict__ xq, int total16) {
  const float inv = 1.0f / scale_p[0];
  const float off = (float)off_p[0];
  int tid = blockIdx.x * blockDim.x + threadIdx.x;
  int stride = gridDim.x * blockDim.x;
  const float4v* x4 = (const float4v*)x;
  int4v* out4 = (int4v*)xq;
  for (int i = tid; i < total16; i += stride) {
    int4v o;
#pragma unroll
    for (int j = 0; j < 4; ++j) {
      float4v v = x4[(size_t)i * 4 + j];
      int r = 0;
#pragma unroll
      for (int e = 0; e < 4; ++e) {
        float q = rintf(v[e] * inv) + off;     // round-half-even, matches jnp.round
        q = fminf(fmaxf(q, -128.0f), 127.0f);
        int qi = (int)q;
        r |= (qi & 0xff) << (8 * e);
      }
      o[j] = r;
    }
    out4[i] = o;
  }
}

// ---------------- weight pack: int32 carrier -> int8 ----------------
__global__ void pack_w_kernel(const int* __restrict__ w,
                              signed char* __restrict__ wq, int total16) {
  int tid = blockIdx.x * blockDim.x + threadIdx.x;
  int stride = gridDim.x * blockDim.x;
  const int4v* w4 = (const int4v*)w;
  int4v* out4 = (int4v*)wq;
  for (int i = tid; i < total16; i += stride) {
    int4v o;
#pragma unroll
    for (int j = 0; j < 4; ++j) {
      int4v v = w4[(size_t)i * 4 + j];
      o[j] = (v[0] & 0xff) | ((v[1] & 0xff) << 8) |
             ((v[2] & 0xff) << 16) | ((v[3] & 0xff) << 24);
    }
    out4[i] = o;
  }
}

// ---- int8 GEMM: 128x256, 4 waves x (64x128), per-group pipelined, 2 blk/CU ----
// A: xq [M][K] int8, B: wq [N][K] int8 (B^T), out fp32 [M][N]
// LDS: B ring-3 (slots 0/16384/32768, stage-ahead-2), A ring-4 (A_OFF+(k&3)*8K,
// stage-ahead-3).  Swizzle (R12, verified 0 conflicts): 64-B rows, physical
// chunk p of row r holds logical chunk p ^ ((r>>1)&3).
// Step t = 8 n-groups of 4 MFMA; B regs ring-3 rotate (issue B(t,g+3) after
// group g); A double-buffered (A(t+1) read at g5, used next step).  Only
// B(t,0..2) are read post-barrier.  lgkm: (2)x6,(5),(4); vmcnt(6)/step.
__global__ __launch_bounds__(256, 2) void gemm_i8_kernel(
    const signed char* __restrict__ A,
    const signed char* __restrict__ B,
    const int* __restrict__ qbias,
    const float* __restrict__ dscale,
    float* __restrict__ out) {
  __shared__ __attribute__((aligned(16))) signed char lds[81920];  // 80 KB

  const int tid  = threadIdx.x;
  const int lane = tid & 63;
  const int wv   = tid >> 6;   // 0..3
  const int wr   = wv >> 1;    // 0..1  (M half: 64 rows)
  const int wc   = wv & 1;     // 0..1  (N half: 128 cols)

  // XCD swizzle: 1376 blocks, 172/XCD; xcd owns tm {4x..4x+3}; 4 adjacent
  // blocks share one 1MB B panel (L2).
  int bid = blockIdx.x;
  int s   = bid >> 3;                  // 0..171
  int tm  = 4 * (bid & 7) + (s & 3);   // 0..31
  int tn  = s >> 2;                    // 0..42

  // ---- staging (pre-swizzled source, linear dest; R12-verified) ----
  const int csw = (((lane & 3) ^ ((lane >> 3) & 3)) << 4);
  const signed char* sA0 = A + (size_t)(tm * BM + wv * 16 + (lane >> 2)) * K_DIM + csw;
  const signed char* sB0 = B + (size_t)(tn * BN + wv * 64 + (lane >> 2)) * K_DIM + csw;
  const int dA0 = wv * 1024 + lane * 16;          // within A slot (frag wv, wv+4)
  const int dB0 = wv * 4096 + lane * 16;          // within B slot (frags wv*4+j)

#define STG_A(KT, AB) do {                                                    \
    gload_lds16(sA0 + (size_t)(KT) * BKB,                      lds + (AB) + dA0);        \
    gload_lds16(sA0 + (size_t)64 * K_DIM + (size_t)(KT) * BKB, lds + (AB) + dA0 + 4096); \
  } while (0)
#define STG_B(KT, SBX) do {                                                   \
    _Pragma("unroll") for (int j = 0; j < 4; ++j)                             \
      gload_lds16(sB0 + (size_t)j * 16 * K_DIM + (size_t)(KT) * BKB,          \
                  lds + (SBX) + dB0 + j * 1024);                              \
  } while (0)

  // ---- ds_read constants (R12-verified conflict-free) ----
  const int rp  = ((((lane >> 4) ^ (lane >> 1)) & 3) << 4);
  const int rdo = (lane & 15) * 64 + rp;
  const int rdA = (wr * 4) * 1024 + rdo;          // + m*1024, within A slot
  const int rdB = (wc * 8) * 1024 + rdo;          // + n*1024, within B slot

#define RD_B(SBX, n) (*(const int4v*)(lds + (SBX) + rdB + (n) * 1024))
#define RD_A4(DST, AB) do {                                                   \
    _Pragma("unroll") for (int m = 0; m < 4; ++m)                             \
      DST[m] = *(const int4v*)(lds + (AB) + rdA + m * 1024); } while (0)

#define LGSB(n) do {                                                          \
    asm volatile("s_waitcnt lgkmcnt(" #n ")" ::: "memory");                   \
    __builtin_amdgcn_sched_barrier(0); } while (0)
#define MMG(AC, BR, NI) do {                                                  \
    __builtin_amdgcn_s_setprio(1);                                            \
    _Pragma("unroll") for (int m = 0; m < 4; ++m)                             \
      acc[m][NI] = __builtin_amdgcn_mfma_i32_16x16x64_i8(                     \
          AC[m], BR, acc[m][NI], 0, 0, 0);                                    \
    __builtin_amdgcn_s_setprio(0); } while (0)

  // One step.  AC = current A regs, AN = next (read at g5 unless LAST).
#define STEP(T, AC, AN, LAST) do {                                            \
    int kA_ = ((T) + 3) & (NT - 1);                                           \
    int kB_ = ((T) + 2) & (NT - 1);                                           \
    STG_A(kA_, ABASE(kA_));                                                   \
    STG_B(kB_, sb2);                                                          \
    br0 = RD_B(sb0, 0); br1 = RD_B(sb0, 1); br2 = RD_B(sb0, 2);               \
    LGSB(2); MMG(AC, br0, 0); br0 = RD_B(sb0, 3);                             \
    LGSB(2); MMG(AC, br1, 1); br1 = RD_B(sb0, 4);                             \
    LGSB(2); MMG(AC, br2, 2); br2 = RD_B(sb0, 5);                             \
    LGSB(2); MMG(AC, br0, 3); br0 = RD_B(sb0, 6);                             \
    LGSB(2); MMG(AC, br1, 4); br1 = RD_B(sb0, 7);                             \
    LGSB(2); MMG(AC, br2, 5);                                                 \
    if (!(LAST)) { RD_A4(AN, ABASE((T) + 1)); }                               \
    if (LAST) { LGSB(1); } else { LGSB(5); }                                  \
    MMG(AC, br0, 6);                                                          \
    if (LAST) { LGSB(0); } else { LGSB(4); }                                  \
    MMG(AC, br1, 7);                                                          \
    asm volatile("s_waitcnt vmcnt(6)" ::: "memory");                          \
    __builtin_amdgcn_s_barrier();                                             \
    int _r = sb0; sb0 = sb1; sb1 = sb2; sb2 = _r;                             \
  } while (0)

  int4v acc[4][8];
#pragma unroll
  for (int i = 0; i < 4; ++i)
#pragma unroll
    for (int j = 0; j < 8; ++j) acc[i][j] = (int4v){0, 0, 0, 0};

  int4v Aev[4], Aod[4], br0, br1, br2;
  int sb0 = 0, sb1 = 16384, sb2 = 32768;

  // ---- prologue: A slots 0,1,2 (ahead-3); B slots 0,1 (ahead-2) ----
  STG_A(0, ABASE(0)); STG_A(1, ABASE(1)); STG_A(2, ABASE(2));
  STG_B(0, 0); STG_B(1, 16384);
  asm volatile("s_waitcnt vmcnt(4)" ::: "memory");   // A0-2,B0 landed; B1 flies
  __builtin_amdgcn_s_barrier();
  RD_A4(Aev, ABASE(0));                              // A(0); drained by 1st LGSB

  for (int t = 0; t < NT - 2; t += 2) {
    STEP(t,     Aev, Aod, 0);
    STEP(t + 1, Aod, Aev, 0);
  }
  STEP(NT - 2, Aev, Aod, 0);
  STEP(NT - 1, Aod, Aev, 1);
  asm volatile("s_waitcnt vmcnt(0) lgkmcnt(0)" ::: "memory");  // drain wrapped tail
#undef STEP
#undef MMG
#undef LGSB
#undef RD_A4
#undef RD_B
#undef STG_B
#undef STG_A

  // ---- epilogue: out[m][n] = (acc + qbias[n]) * dscale[n] ----
  const int col = lane & 15;
  const int rb  = (lane >> 4) * 4;
  const int gm0 = tm * BM + wr * 64;
  const int gn0 = tn * BN + wc * 128;
#pragma unroll
  for (int n = 0; n < 8; ++n) {
    int gn = gn0 + n * 16 + col;
    float ds = dscale[gn];
    int qb = qbias[gn];
#pragma unroll
    for (int m = 0; m < 4; ++m) {
      int gm = gm0 + m * 16 + rb;
#pragma unroll
      for (int j = 0; j < 4; ++j)
        out[(size_t)(gm + j) * N_DIM + gn] = (float)(acc[m][n][j] + qb) * ds;
    }
  }
}

extern "C" void kernel_launch(void* const* d_in, const int* in_sizes, int n_in,
                              void* d_out, int out_size, void* d_ws, size_t ws_size,
                              hipStream_t stream) {
  const float* x      = (const float*)d_in[0];
  const int*   w      = (const int*)d_in[1];
  const float* dscale = (const float*)d_in[2];
  const float* iscale = (const float*)d_in[3];
  const int*   ioff   = (const int*)d_in[4];
  const int*   qbias  = (const int*)d_in[5];
  float* out = (float*)d_out;

  const size_t xq_bytes = (size_t)M_DIM * K_DIM;        // 16 MB
  const size_t wq_bytes = (size_t)N_DIM * K_DIM;        // 45 MB
  if (ws_size < xq_bytes + wq_bytes) return;

  signed char* xq = (signed char*)d_ws;
  signed char* wq = (signed char*)d_ws + xq_bytes;

  quant_x_kernel<<<2048, 256, 0, stream>>>(x, iscale, ioff, xq, M_DIM * K_DIM / 16);
  pack_w_kernel<<<2048, 256, 0, stream>>>(w, wq, N_DIM * K_DIM / 16);
  gemm_i8_kernel<<<NTM * NTN, 256, 0, stream>>>(xq, wq, qbias, dscale, out);
}